// Round 8
// baseline (132.603 us; speedup 1.0000x reference)
//
#include <hip/hip_runtime.h>
#include <math.h>

#define Lc 128
#define Rc 1024
#define Pc 8
#define Ec 64
#define Fc 64

#define RT 64        // r per block (lane = r)
#define LT 8         // l per block (all handled by every wave, register-blocked)
#define NW 4         // waves per block (256 threads)
#define EW 8         // e's per wave (block covers 32 e; z splits the other 32)
#define NBLK 512     // 16 rt x 16 lt x 2 z

// exp(-((d-mu)/sigma)^2) = exp2(-(C*(d-mu))^2), C = (1/0.15625)*sqrt(log2(e))
#define CSCALE   7.68718341623328f
#define MU_STEP  0.15873015873015873f   // 10/63
#define MUC      (MU_STEP * CSCALE)

// 64 KB static LDS: halves the compiler-visible occupancy bound to
// 2 blocks/CU = 2 waves/EU  ->  register budget 512/2 = 256 VGPRs.
// (Grid is 512 blocks = 2/CU anyway, so real occupancy is unchanged.)
// Slices [0..NW): staging. Slices [NW..2*NW): final-reduce scratch (used!).
__global__ __launch_bounds__(256, 2)
void ff_fused(const float* __restrict__ lig_feat,
              const float* __restrict__ rec_feat,
              const float* __restrict__ lig_coords,
              const float* __restrict__ rec_coords,
              float* __restrict__ partial)
{
    __shared__ float4 staged[2 * NW][8][64];   // 64 KB

    const int tid = threadIdx.x;
    const int rr  = tid & 63;
    const int w   = __builtin_amdgcn_readfirstlane(tid >> 6);

    // grid: bid&7 -> XCD chunk (2 r-tiles per XCD => 2MB rec slice, L2-resident)
    const int bid  = blockIdx.x;
    const int rt   = (bid & 7) * 2 + ((bid >> 3) & 1);
    const int rest = bid >> 4;
    const int lt   = rest & 15;
    const int z    = rest >> 4;
    const int r0   = rt * RT;
    const int l0   = lt * LT;
    const int e0   = z * 32 + w * EW;    // this wave's private e-range

    const int r = r0 + rr;
    const float rcx = rec_coords[r * 3 + 0];
    const float rcy = rec_coords[r * 3 + 1];
    const float rcz = rec_coords[r * 3 + 2];

    // scaled distances, 8 l x 8 p (lig side wave-uniform -> scalar loads)
    float dscC[Pc][LT];
    #pragma unroll
    for (int li = 0; li < LT; ++li) {
        #pragma unroll
        for (int p = 0; p < Pc; ++p) {
            const float* lcp = lig_coords + ((size_t)p * Lc + l0 + li) * 3;
            float dx = lcp[0] - rcx;
            float dy = lcp[1] - rcy;
            float dz = lcp[2] - rcz;
            dscC[p][li] = sqrtf(dx * dx + dy * dy + dz * dz) * CSCALE;
        }
    }

    // staging lane roles: lane = (rsub, f4s); rows rsub+8j, j=0..7
    const int f4s  = rr & 7;
    const int rsub = rr >> 3;
    const float* gbr = rec_feat + ((size_t)r0 + rsub) * (Ec * Fc)
                       + (size_t)e0 * Fc + f4s * 4;
    // addr(row j, te, fh) = gbr + j*8*4096 + te*64 + fh*32

    float4 pf[8];
    #pragma unroll
    for (int j = 0; j < 8; ++j)
        pf[j] = *(const float4*)(gbr + (size_t)j * 8 * (Ec * Fc));

    float us[Pc];
    #pragma unroll
    for (int p = 0; p < Pc; ++p) us[p] = 0.f;

    // ---- main loop: 8 e-steps x 2 f-halves, NO barriers (wave-private slice) ----
    for (int te = 0; te < EW; ++te) {
        const int e = e0 + te;
        float acc[LT];
        #pragma unroll
        for (int li = 0; li < LT; ++li) acc[li] = 0.f;

        #pragma unroll
        for (int fh = 0; fh < 2; ++fh) {
            // write this half into the wave's slice (XOR slot swizzle)
            #pragma unroll
            for (int j = 0; j < 8; ++j)
                staged[w][f4s][(rsub + 8 * j) ^ f4s] = pf[j];

            // issue next half's global loads (hide latency under the dot)
            const int nxt = te * 2 + fh + 1;
            if (nxt < EW * 2) {
                const int ten = nxt >> 1;
                const int fhn = nxt & 1;
                #pragma unroll
                for (int j = 0; j < 8; ++j)
                    pf[j] = *(const float4*)(gbr + (size_t)j * 8 * (Ec * Fc)
                                             + ten * Fc + fhn * 32);
            }

            // dot this f-half: lane reads its own r-row; lig via SGPR operands
            #pragma unroll
            for (int s = 0; s < 8; ++s) {
                const float4 rv = staged[w][s][rr ^ s];
                const float* lr = lig_feat + ((size_t)l0 * Ec + e) * Fc + fh * 32 + s * 4;
                #pragma unroll
                for (int li = 0; li < LT; ++li) {
                    const float* lrl = lr + (size_t)li * (Ec * Fc);
                    acc[li] = fmaf(lrl[0], rv.x, acc[li]);
                    acc[li] = fmaf(lrl[1], rv.y, acc[li]);
                    acc[li] = fmaf(lrl[2], rv.z, acc[li]);
                    acc[li] = fmaf(lrl[3], rv.w, acc[li]);
                }
            }
        }

        // fold atn[l, r, e] into the 8 pose accumulators
        const float musC = (float)e * MUC;
        #pragma unroll
        for (int li = 0; li < LT; ++li) {
            const float a = acc[li];
            #pragma unroll
            for (int p = 0; p < Pc; ++p) {
                const float tt = dscC[p][li] - musC;
                us[p] = fmaf(a, __builtin_amdgcn_exp2f(-(tt * tt)), us[p]);
            }
        }
    }

    // ---- wave butterfly over r-lanes, then block reduce via upper LDS half ----
    #pragma unroll
    for (int p = 0; p < Pc; ++p) {
        float v = us[p];
        #pragma unroll
        for (int off = 32; off >= 1; off >>= 1)
            v += __shfl_xor(v, off, 64);
        us[p] = v;
    }
    if (rr == 0) {
        float* wred = (float*)&staged[NW + w][0][0];   // upper half: reduce scratch
        #pragma unroll
        for (int p = 0; p < Pc; ++p) wred[p] = us[p];
    }
    __syncthreads();   // the only barrier in the kernel
    if (tid < Pc) {
        float s = 0.f;
        #pragma unroll
        for (int k = 0; k < NW; ++k)
            s += ((const float*)&staged[NW + k][0][0])[tid];
        partial[(size_t)bid * Pc + tid] = s;
    }
}

// reduce NBLK block-partials x 8 poses -> 8 outputs
__global__ void ff_reduce(const float* __restrict__ partial, float* __restrict__ out)
{
    const int w    = threadIdx.x >> 6;  // pose = wave id (8 waves)
    const int lane = threadIdx.x & 63;
    float v = 0.f;
    #pragma unroll
    for (int j = 0; j < NBLK / 64; ++j)
        v += partial[(size_t)(lane + 64 * j) * Pc + w];
    #pragma unroll
    for (int off = 32; off >= 1; off >>= 1)
        v += __shfl_xor(v, off, 64);
    if (lane == 0) out[w] = 0.1f * v;
}

extern "C" void kernel_launch(void* const* d_in, const int* in_sizes, int n_in,
                              void* d_out, int out_size, void* d_ws, size_t ws_size,
                              hipStream_t stream)
{
    const float* lig_feat   = (const float*)d_in[0];
    const float* rec_feat   = (const float*)d_in[1];
    const float* lig_coords = (const float*)d_in[2];
    const float* rec_coords = (const float*)d_in[3];
    float* out     = (float*)d_out;
    float* partial = (float*)d_ws;   // NBLK * 8 * 4 = 16 KB

    ff_fused<<<NBLK, 256, 0, stream>>>(lig_feat, rec_feat, lig_coords, rec_coords, partial);
    ff_reduce<<<1, 512, 0, stream>>>(partial, out);
}

// Round 9
// 103.956 us; speedup vs baseline: 1.2756x; 1.2756x over previous
//
#include <hip/hip_runtime.h>
#include <math.h>

#define Lc 128
#define Rc 1024
#define Pc 8
#define Ec 64
#define Fc 64

// ---- kernel A (attention GEMM) tiling ----
#define RT 64        // r per block (lane = r)
#define LT 8         // l per block (register-blocked in acc[8])
#define NWA 4        // waves per block
#define EZ 4         // e-range splits -> grid z
#define NBLKA ((Rc / RT) * (Lc / LT) * EZ)   // 16*16*4 = 1024

// ---- kernel B (RBF fold) tiling ----
#define RB 256       // r per block
#define NBLKB (Lc * (Rc / RB))               // 128*4 = 512

// exp(-((d-mu)/sigma)^2) = exp2(-(C*(d-mu))^2), C = (1/0.15625)*sqrt(log2(e))
#define CSCALE   7.68718341623328f
#define MU_STEP  0.15873015873015873f   // 10/63
#define MUC      (MU_STEP * CSCALE)

// ============ kernel A: atn[l][e][r] = sum_f lig[l,e,f]*rec[r,e,f] ============
// Per-thread live state ~60 regs (acc[8] + pf[8] + addr): spill-proof.
__global__ __launch_bounds__(256, 2)
void ff_atn(const float* __restrict__ lig_feat,
            const float* __restrict__ rec_feat,
            float* __restrict__ atn)
{
    __shared__ float4 staged[NWA][8][64];   // 32 KB, wave-private slices

    const int tid = threadIdx.x;
    const int rr  = tid & 63;
    const int w   = __builtin_amdgcn_readfirstlane(tid >> 6);

    // bid&7 -> XCD chunk: each XCD sees 2 r-tiles (2 MB rec slice, L2-resident)
    const int bid  = blockIdx.x;
    const int rt   = (bid & 7) * 2 + ((bid >> 3) & 1);
    const int rest = bid >> 4;
    const int lt   = rest & 15;
    const int z    = rest >> 4;              // 0..3
    const int r0   = rt * RT;
    const int l0   = lt * LT;
    const int e0   = z * 16 + w * 4;         // this wave's private 4-e range

    // staging lane roles: lane = (rsub, f4s); stages rows rsub+8j, j=0..7
    const int f4s  = rr & 7;
    const int rsub = rr >> 3;
    const float* gbr = rec_feat + ((size_t)r0 + rsub) * (Ec * Fc)
                       + (size_t)e0 * Fc + f4s * 4;

    float4 pf[8];
    #pragma unroll
    for (int j = 0; j < 8; ++j)
        pf[j] = *(const float4*)(gbr + (size_t)j * 8 * (Ec * Fc));

    for (int te = 0; te < 4; ++te) {
        const int e = e0 + te;
        float acc[LT];
        #pragma unroll
        for (int li = 0; li < LT; ++li) acc[li] = 0.f;

        #pragma unroll
        for (int fh = 0; fh < 2; ++fh) {
            // write this f-half into the wave's slice (XOR slot swizzle)
            #pragma unroll
            for (int j = 0; j < 8; ++j)
                staged[w][f4s][(rsub + 8 * j) ^ f4s] = pf[j];

            // prefetch next half (hide L2/HBM latency under the dot)
            const int nxt = te * 2 + fh + 1;
            if (nxt < 8) {
                const int ten = nxt >> 1;
                const int fhn = nxt & 1;
                #pragma unroll
                for (int j = 0; j < 8; ++j)
                    pf[j] = *(const float4*)(gbr + (size_t)j * 8 * (Ec * Fc)
                                             + ten * Fc + fhn * 32);
            }

            // dot: lane reads its own r-row from LDS; lig via SGPR operands
            #pragma unroll
            for (int s = 0; s < 8; ++s) {
                const float4 rv = staged[w][s][rr ^ s];
                const float* lr = lig_feat + ((size_t)l0 * Ec + e) * Fc + fh * 32 + s * 4;
                #pragma unroll
                for (int li = 0; li < LT; ++li) {
                    const float* lrl = lr + (size_t)li * (Ec * Fc);
                    acc[li] = fmaf(lrl[0], rv.x, acc[li]);
                    acc[li] = fmaf(lrl[1], rv.y, acc[li]);
                    acc[li] = fmaf(lrl[2], rv.z, acc[li]);
                    acc[li] = fmaf(lrl[3], rv.w, acc[li]);
                }
            }
        }

        // store atn[l][e][r]: coalesced dwords over rr
        #pragma unroll
        for (int li = 0; li < LT; ++li)
            atn[((size_t)(l0 + li) * Ec + e) * Rc + r0 + rr] = acc[li];
    }
}

// ============ kernel B: Us[p] += sum_{l,r,e} atn[l,e,r]*exp2(-(dsc[p]-mu_e*C)^2) ====
// Per-thread state ~35 regs.
__global__ __launch_bounds__(256, 2)
void ff_fold(const float* __restrict__ atn,
             const float* __restrict__ lig_coords,
             const float* __restrict__ rec_coords,
             float* __restrict__ partial)
{
    __shared__ float wsum[4][Pc];

    const int tid = threadIdx.x;
    const int rr  = tid & 63;
    const int w   = tid >> 6;

    const int bid = blockIdx.x;
    const int l   = bid >> 2;          // 0..127 (uniform -> lig scalar loads)
    const int r   = (bid & 3) * RB + tid;

    const float rcx = rec_coords[r * 3 + 0];
    const float rcy = rec_coords[r * 3 + 1];
    const float rcz = rec_coords[r * 3 + 2];

    float dsc[Pc];
    #pragma unroll
    for (int p = 0; p < Pc; ++p) {
        const float* lcp = lig_coords + ((size_t)p * Lc + l) * 3;
        float dx = lcp[0] - rcx;
        float dy = lcp[1] - rcy;
        float dz = lcp[2] - rcz;
        dsc[p] = sqrtf(dx * dx + dy * dy + dz * dz) * CSCALE;
    }

    const float* base = atn + (size_t)l * (Ec * Rc) + r;

    float us[Pc];
    #pragma unroll
    for (int p = 0; p < Pc; ++p) us[p] = 0.f;

    for (int eo = 0; eo < 8; ++eo) {
        float a[8];
        #pragma unroll
        for (int j = 0; j < 8; ++j)
            a[j] = base[(size_t)(eo * 8 + j) * Rc];   // coalesced over lanes
        #pragma unroll
        for (int j = 0; j < 8; ++j) {
            const float musC = (float)(eo * 8 + j) * MUC;
            #pragma unroll
            for (int p = 0; p < Pc; ++p) {
                const float t = dsc[p] - musC;
                us[p] = fmaf(a[j], __builtin_amdgcn_exp2f(-(t * t)), us[p]);
            }
        }
    }

    // wave butterfly, then block reduce
    #pragma unroll
    for (int p = 0; p < Pc; ++p) {
        float v = us[p];
        #pragma unroll
        for (int off = 32; off >= 1; off >>= 1)
            v += __shfl_xor(v, off, 64);
        us[p] = v;
    }
    if (rr == 0) {
        #pragma unroll
        for (int p = 0; p < Pc; ++p) wsum[w][p] = us[p];
    }
    __syncthreads();
    if (tid < Pc) {
        float s = 0.f;
        #pragma unroll
        for (int k = 0; k < 4; ++k) s += wsum[k][tid];
        partial[(size_t)bid * Pc + tid] = s;
    }
}

// reduce NBLKB block-partials x 8 poses -> 8 outputs
__global__ void ff_reduce(const float* __restrict__ partial, float* __restrict__ out)
{
    const int w    = threadIdx.x >> 6;  // pose = wave id (8 waves)
    const int lane = threadIdx.x & 63;
    float v = 0.f;
    #pragma unroll
    for (int j = 0; j < NBLKB / 64; ++j)
        v += partial[(size_t)(lane + 64 * j) * Pc + w];
    #pragma unroll
    for (int off = 32; off >= 1; off >>= 1)
        v += __shfl_xor(v, off, 64);
    if (lane == 0) out[w] = 0.1f * v;
}

extern "C" void kernel_launch(void* const* d_in, const int* in_sizes, int n_in,
                              void* d_out, int out_size, void* d_ws, size_t ws_size,
                              hipStream_t stream)
{
    const float* lig_feat   = (const float*)d_in[0];
    const float* rec_feat   = (const float*)d_in[1];
    const float* lig_coords = (const float*)d_in[2];
    const float* rec_coords = (const float*)d_in[3];
    float* out     = (float*)d_out;
    float* partial = (float*)d_ws;                         // 512*8*4 = 16 KB
    float* atn     = (float*)((char*)d_ws + 16384);        // 128*64*1024*4 = 32 MB

    ff_atn<<<NBLKA, 256, 0, stream>>>(lig_feat, rec_feat, atn);
    ff_fold<<<NBLKB, 256, 0, stream>>>(atn, lig_coords, rec_coords, partial);
    ff_reduce<<<1, 512, 0, stream>>>(partial, out);
}

// Round 10
// 96.599 us; speedup vs baseline: 1.3727x; 1.0762x over previous
//
#include <hip/hip_runtime.h>
#include <math.h>

#define Lc 128
#define Rc 1024
#define Pc 8
#define Ec 64
#define Fc 64

// ---- kernel A (attention GEMM) ----
#define RT 64        // r per block (lane = r)
#define LT 8         // l per block (register-blocked in acc[8])
#define NWA 4        // waves per block
#define NBLKA 512    // 16 rt * 16 lt * 2 z

// ---- kernel B (RBF fold) ----
#define RB 256
#define NBLKB (Lc * (Rc / RB))   // 512

// exp(-((d-mu)/sigma)^2) = exp2(-(C*(d-mu))^2), C = (1/0.15625)*sqrt(log2(e))
#define CSCALE   7.68718341623328f
#define MU_STEP  0.15873015873015873f   // 10/63
#define MUC      (MU_STEP * CSCALE)

// ======== kernel A: atn[l][e][r] = sum_f lig[l,e,f]*rec[r,e,f] ========
// No SGPR data path (lig base laundered to VGPRs), no staging registers
// (global_load_lds DMA), wave-private double-buffered LDS, no loop barriers.
__global__ __launch_bounds__(256, 2)
void ff_atn(const float* __restrict__ lig_feat,
            const float* __restrict__ rec_feat,
            float* __restrict__ atn)
{
    // [wave][buf][row*8 + f4slot], slot holds rec col (f4slot ^ (row&7)). 64 KB.
    __shared__ float4 staged[NWA][2][512];

    const int tid = threadIdx.x;
    const int rr  = tid & 63;
    const int w   = __builtin_amdgcn_readfirstlane(tid >> 6);

    // XCD swizzle: each XCD owns 2 consecutive r-tiles (2 MB rec slice, L2-resident)
    const int bid  = blockIdx.x;
    const int rt   = (bid & 7) * 2 + ((bid >> 3) & 1);
    const int rest = bid >> 4;
    const int lt   = rest & 15;
    const int z    = rest >> 4;            // 0..1
    const int r0   = rt * RT;
    const int l0   = lt * LT;
    const int e0   = z * 32 + w * 8;       // wave-private 8-e range

    // launder lig base into VGPRs: uniformity unprovable -> per-lane VMEM
    // broadcast loads instead of the s_load explosion (the round-4..9 spill cause)
    unsigned long long lig_u = (unsigned long long)(uintptr_t)lig_feat;
    asm("" : "+v"(lig_u));
    const float* lig_v = (const float*)(uintptr_t)lig_u;

    // DMA lane roles: lane=(rg,c): row-in-group rg=rr>>3, slot c=rr&7.
    // Source col pre-swizzled so linear LDS DMA lands XOR-swizzled content.
    const int rg   = rr >> 3;
    const int colp = (rr & 7) ^ rg;
    const int rx   = rr & 7;
    const float* gdma = rec_feat + ((size_t)r0 + rg) * (Ec * Fc)
                        + (size_t)e0 * Fc + colp * 4;

    // prologue: stage step 0 (te=0, fh=0) into buf 0
    #pragma unroll
    for (int j = 0; j < 8; ++j)
        __builtin_amdgcn_global_load_lds(
            (const __attribute__((address_space(1))) void*)(gdma + (size_t)j * 8 * (Ec * Fc)),
            (__attribute__((address_space(3))) void*)&staged[w][0][j * 64], 16, 0, 0);

    float acc[LT];
    #pragma unroll
    for (int li = 0; li < LT; ++li) acc[li] = 0.f;

    for (int t = 0; t < 16; ++t) {          // 8 e x 2 f-halves
        const int e  = e0 + (t >> 1);
        const int fh = t & 1;

        // wait for this buffer's DMA (wave-private: no barrier needed)
        asm volatile("s_waitcnt vmcnt(0)" ::: "memory");
        __builtin_amdgcn_sched_barrier(0);

        const float4* sb = &staged[w][t & 1][0];
        #pragma unroll
        for (int s = 0; s < 8; ++s) {
            const float4 rv = sb[rr * 8 + (s ^ rx)];   // all 32 banks: conflict-free
            #pragma unroll
            for (int li = 0; li < LT; ++li) {
                const float4 lv = *(const float4*)(lig_v
                    + ((size_t)(l0 + li) * Ec + e) * Fc + fh * 32 + s * 4);
                acc[li] = fmaf(lv.x, rv.x, acc[li]);
                acc[li] = fmaf(lv.y, rv.y, acc[li]);
                acc[li] = fmaf(lv.z, rv.z, acc[li]);
                acc[li] = fmaf(lv.w, rv.w, acc[li]);
            }
        }

        // issue next step's DMA into the other buffer (after this step's
        // lig loads so vmcnt ordering doesn't serialize the dot on fresh DMA)
        if (t < 15) {
            const int tn = t + 1;
            const float* gs = gdma + (tn >> 1) * Fc + (tn & 1) * 32;
            #pragma unroll
            for (int j = 0; j < 8; ++j)
                __builtin_amdgcn_global_load_lds(
                    (const __attribute__((address_space(1))) void*)(gs + (size_t)j * 8 * (Ec * Fc)),
                    (__attribute__((address_space(3))) void*)&staged[w][tn & 1][j * 64], 16, 0, 0);
        }

        if (fh) {   // atn row complete: coalesced store, reset accumulators
            #pragma unroll
            for (int li = 0; li < LT; ++li) {
                atn[((size_t)(l0 + li) * Ec + e) * Rc + r0 + rr] = acc[li];
                acc[li] = 0.f;
            }
        }
    }
}

// ======== kernel B: Us[p] += sum_{l,r,e} atn[l,e,r]*exp2(-(dsc[p]-mu_e*C)^2) ====
__global__ __launch_bounds__(256, 2)
void ff_fold(const float* __restrict__ atn,
             const float* __restrict__ lig_coords,
             const float* __restrict__ rec_coords,
             float* __restrict__ partial)
{
    __shared__ float wsum[4][Pc];

    const int tid = threadIdx.x;
    const int rr  = tid & 63;
    const int w   = tid >> 6;

    const int bid = blockIdx.x;
    const int l   = bid >> 2;
    const int r   = (bid & 3) * RB + tid;

    const float rcx = rec_coords[r * 3 + 0];
    const float rcy = rec_coords[r * 3 + 1];
    const float rcz = rec_coords[r * 3 + 2];

    float dsc[Pc];
    #pragma unroll
    for (int p = 0; p < Pc; ++p) {
        const float* lcp = lig_coords + ((size_t)p * Lc + l) * 3;
        float dx = lcp[0] - rcx;
        float dy = lcp[1] - rcy;
        float dz = lcp[2] - rcz;
        dsc[p] = sqrtf(dx * dx + dy * dy + dz * dz) * CSCALE;
    }

    const float* base = atn + (size_t)l * (Ec * Rc) + r;

    float us[Pc];
    #pragma unroll
    for (int p = 0; p < Pc; ++p) us[p] = 0.f;

    for (int eo = 0; eo < 8; ++eo) {
        float a[8];
        #pragma unroll
        for (int j = 0; j < 8; ++j)
            a[j] = base[(size_t)(eo * 8 + j) * Rc];   // coalesced over lanes
        #pragma unroll
        for (int j = 0; j < 8; ++j) {
            const float musC = (float)(eo * 8 + j) * MUC;
            #pragma unroll
            for (int p = 0; p < Pc; ++p) {
                const float t = dsc[p] - musC;
                us[p] = fmaf(a[j], __builtin_amdgcn_exp2f(-(t * t)), us[p]);
            }
        }
    }

    #pragma unroll
    for (int p = 0; p < Pc; ++p) {
        float v = us[p];
        #pragma unroll
        for (int off = 32; off >= 1; off >>= 1)
            v += __shfl_xor(v, off, 64);
        us[p] = v;
    }
    if (rr == 0) {
        #pragma unroll
        for (int p = 0; p < Pc; ++p) wsum[w][p] = us[p];
    }
    __syncthreads();
    if (tid < Pc) {
        float s = 0.f;
        #pragma unroll
        for (int k = 0; k < 4; ++k) s += wsum[k][tid];
        partial[(size_t)bid * Pc + tid] = s;
    }
}

// reduce NBLKB block-partials x 8 poses -> 8 outputs
__global__ void ff_reduce(const float* __restrict__ partial, float* __restrict__ out)
{
    const int w    = threadIdx.x >> 6;
    const int lane = threadIdx.x & 63;
    float v = 0.f;
    #pragma unroll
    for (int j = 0; j < NBLKB / 64; ++j)
        v += partial[(size_t)(lane + 64 * j) * Pc + w];
    #pragma unroll
    for (int off = 32; off >= 1; off >>= 1)
        v += __shfl_xor(v, off, 64);
    if (lane == 0) out[w] = 0.1f * v;
}

extern "C" void kernel_launch(void* const* d_in, const int* in_sizes, int n_in,
                              void* d_out, int out_size, void* d_ws, size_t ws_size,
                              hipStream_t stream)
{
    const float* lig_feat   = (const float*)d_in[0];
    const float* rec_feat   = (const float*)d_in[1];
    const float* lig_coords = (const float*)d_in[2];
    const float* rec_coords = (const float*)d_in[3];
    float* out     = (float*)d_out;
    float* partial = (float*)d_ws;                    // 512*8*4 = 16 KB
    float* atn     = (float*)((char*)d_ws + 16384);   // 32 MB

    ff_atn<<<NBLKA, 256, 0, stream>>>(lig_feat, rec_feat, atn);
    ff_fold<<<NBLKB, 256, 0, stream>>>(atn, lig_coords, rec_coords, partial);
    ff_reduce<<<1, 512, 0, stream>>>(partial, out);
}

// Round 11
// 55.269 us; speedup vs baseline: 2.3992x; 1.7478x over previous
//
#include <hip/hip_runtime.h>
#include <math.h>

#define Lc 128
#define Rc 1024
#define Pc 8
#define Ec 64
#define Fc 64

// exp(-((d-mu)/sigma)^2) = exp2(-(C*(d-mu))^2), C = (1/0.15625)*sqrt(log2(e))
#define CSCALE   7.68718341623328f
#define MU_STEP  0.15873015873015873f   // 10/63
#define MUC      (MU_STEP * CSCALE)

#define NBLKM 512    // ff_mfma blocks: 16 ng x 8 mt x 4 ez

typedef __attribute__((ext_vector_type(8))) short short8;   // 8 bf16 (4 VGPRs)
typedef __attribute__((ext_vector_type(4))) float f32x4;

__device__ __forceinline__ unsigned short bf16_rn(float x) {
    unsigned int u = __float_as_uint(x);
    u += 0x7FFF + ((u >> 16) & 1);
    return (unsigned short)(u >> 16);
}
__device__ __forceinline__ float bf16_f32(unsigned short b) {
    return __uint_as_float(((unsigned int)b) << 16);
}

// ---- split-convert f32 -> (hi,lo) bf16, layout [g=row*64+e][hi:0..63 | lo:64..127] ----
__global__ __launch_bounds__(256)
void ff_cvt(const float* __restrict__ src, unsigned short* __restrict__ dst, int n4)
{
    int i = blockIdx.x * 256 + threadIdx.x;
    if (i >= n4) return;
    float4 v = ((const float4*)src)[i];
    int s0 = i * 4;
    size_t g = (size_t)(s0 >> 6);
    int kb = s0 & 63;
    ushort4 h, l;
    h.x = bf16_rn(v.x); l.x = bf16_rn(v.x - bf16_f32(h.x));
    h.y = bf16_rn(v.y); l.y = bf16_rn(v.y - bf16_f32(h.y));
    h.z = bf16_rn(v.z); l.z = bf16_rn(v.z - bf16_f32(h.z));
    h.w = bf16_rn(v.w); l.w = bf16_rn(v.w - bf16_f32(h.w));
    *(ushort4*)(dst + g * 128 + kb)      = h;
    *(ushort4*)(dst + g * 128 + 64 + kb) = l;
}

// ---- fused: per (16l x 16r) C-tile, per e: 6 split-MFMAs -> fold exp2 into us[p] ----
// C/D layout (verified, m89): col r = lane&15, row l_off = (lane>>4)*4 + reg.
// A-frag: lane holds A[lane&15, (lane>>4)*8 + 0..7]; B-frag: B[(lane>>4)*8+0..7, lane&15].
__global__ __launch_bounds__(256, 2)
void ff_mfma(const unsigned short* __restrict__ ligP,
             const unsigned short* __restrict__ recP,
             const float* __restrict__ lig_coords,
             const float* __restrict__ rec_coords,
             float* __restrict__ partial)
{
    __shared__ float wsum[4][Pc];

    const int tid  = threadIdx.x;
    const int lane = tid & 63;
    const int w    = tid >> 6;
    const int n16  = lane & 15;
    const int kg   = lane >> 4;

    // bid -> (ng, mt, ez); bid&7 = XCD (round-robin dispatch): each XCD owns
    // 2 n-groups -> 128 rec rows = 2 MB recP slice, L2-resident.
    const int bid = blockIdx.x;
    const int loc = bid >> 3;
    const int ng  = (bid & 7) * 2 + (loc & 1);
    const int mt  = (loc >> 1) & 7;
    const int ez  = loc >> 4;              // 0..3
    const int nt  = ng * 4 + w;            // this wave's ntile 0..63
    const int r   = nt * 16 + n16;
    const int e0  = ez * 16;

    // per-lane distances for (8 poses) x (4 l's of this lane)
    const float rcx = rec_coords[r * 3 + 0];
    const float rcy = rec_coords[r * 3 + 1];
    const float rcz = rec_coords[r * 3 + 2];
    float dsc[Pc][4];
    #pragma unroll
    for (int reg = 0; reg < 4; ++reg) {
        const int l = mt * 16 + kg * 4 + reg;
        #pragma unroll
        for (int p = 0; p < Pc; ++p) {
            const float* lcp = lig_coords + ((size_t)p * Lc + l) * 3;
            float dx = lcp[0] - rcx;
            float dy = lcp[1] - rcy;
            float dz = lcp[2] - rcz;
            dsc[p][reg] = sqrtf(dx * dx + dy * dy + dz * dz) * CSCALE;
        }
    }

    // fragment base pointers (per-lane, 16B loads; e-step advances by 128)
    const unsigned short* ap = ligP + ((size_t)(mt * 16 + n16) * Ec + e0) * 128 + kg * 8;
    const unsigned short* bp = recP + ((size_t)r * Ec + e0) * 128 + kg * 8;

    short8 Ah0 = *(const short8*)(ap);
    short8 Ah1 = *(const short8*)(ap + 32);
    short8 Al0 = *(const short8*)(ap + 64);
    short8 Al1 = *(const short8*)(ap + 96);
    short8 Bh0 = *(const short8*)(bp);
    short8 Bh1 = *(const short8*)(bp + 32);
    short8 Bl0 = *(const short8*)(bp + 64);
    short8 Bl1 = *(const short8*)(bp + 96);

    float us[Pc];
    #pragma unroll
    for (int p = 0; p < Pc; ++p) us[p] = 0.f;

    for (int te = 0; te < 16; ++te) {
        // prefetch next e's fragments (fold below hides the L2 latency)
        short8 nAh0 = Ah0, nAh1 = Ah1, nAl0 = Al0, nAl1 = Al1;
        short8 nBh0 = Bh0, nBh1 = Bh1, nBl0 = Bl0, nBl1 = Bl1;
        if (te < 15) {
            const unsigned short* an = ap + (size_t)(te + 1) * 128;
            const unsigned short* bn = bp + (size_t)(te + 1) * 128;
            nAh0 = *(const short8*)(an);
            nAh1 = *(const short8*)(an + 32);
            nAl0 = *(const short8*)(an + 64);
            nAl1 = *(const short8*)(an + 96);
            nBh0 = *(const short8*)(bn);
            nBh1 = *(const short8*)(bn + 32);
            nBl0 = *(const short8*)(bn + 64);
            nBl1 = *(const short8*)(bn + 96);
        }

        // atn tile for this e: hh + al*bh + ah*bl (drop al*bl, ~2^-18 rel)
        f32x4 acc = {0.f, 0.f, 0.f, 0.f};
        acc = __builtin_amdgcn_mfma_f32_16x16x32_bf16(Ah0, Bh0, acc, 0, 0, 0);
        acc = __builtin_amdgcn_mfma_f32_16x16x32_bf16(Ah1, Bh1, acc, 0, 0, 0);
        acc = __builtin_amdgcn_mfma_f32_16x16x32_bf16(Al0, Bh0, acc, 0, 0, 0);
        acc = __builtin_amdgcn_mfma_f32_16x16x32_bf16(Al1, Bh1, acc, 0, 0, 0);
        acc = __builtin_amdgcn_mfma_f32_16x16x32_bf16(Ah0, Bl0, acc, 0, 0, 0);
        acc = __builtin_amdgcn_mfma_f32_16x16x32_bf16(Ah1, Bl1, acc, 0, 0, 0);

        // fold into pose accumulators
        const float musC = (float)(e0 + te) * MUC;
        #pragma unroll
        for (int reg = 0; reg < 4; ++reg) {
            const float a = acc[reg];
            #pragma unroll
            for (int p = 0; p < Pc; ++p) {
                const float t = dsc[p][reg] - musC;
                us[p] = fmaf(a, __builtin_amdgcn_exp2f(-(t * t)), us[p]);
            }
        }

        Ah0 = nAh0; Ah1 = nAh1; Al0 = nAl0; Al1 = nAl1;
        Bh0 = nBh0; Bh1 = nBh1; Bl0 = nBl0; Bl1 = nBl1;
    }

    // butterfly over 64 lanes, then across the 4 waves
    #pragma unroll
    for (int p = 0; p < Pc; ++p) {
        float v = us[p];
        #pragma unroll
        for (int off = 32; off >= 1; off >>= 1)
            v += __shfl_xor(v, off, 64);
        us[p] = v;
    }
    if (lane == 0) {
        #pragma unroll
        for (int p = 0; p < Pc; ++p) wsum[w][p] = us[p];
    }
    __syncthreads();
    if (tid < Pc) {
        float s = 0.f;
        #pragma unroll
        for (int k = 0; k < 4; ++k) s += wsum[k][tid];
        partial[(size_t)bid * Pc + tid] = s;
    }
}

// reduce NBLKM block-partials x 8 poses -> 8 outputs
__global__ void ff_reduce(const float* __restrict__ partial, float* __restrict__ out)
{
    const int w    = threadIdx.x >> 6;
    const int lane = threadIdx.x & 63;
    float v = 0.f;
    #pragma unroll
    for (int j = 0; j < NBLKM / 64; ++j)
        v += partial[(size_t)(lane + 64 * j) * Pc + w];
    #pragma unroll
    for (int off = 32; off >= 1; off >>= 1)
        v += __shfl_xor(v, off, 64);
    if (lane == 0) out[w] = 0.1f * v;
}

extern "C" void kernel_launch(void* const* d_in, const int* in_sizes, int n_in,
                              void* d_out, int out_size, void* d_ws, size_t ws_size,
                              hipStream_t stream)
{
    const float* lig_feat   = (const float*)d_in[0];
    const float* rec_feat   = (const float*)d_in[1];
    const float* lig_coords = (const float*)d_in[2];
    const float* rec_coords = (const float*)d_in[3];
    float* out = (float*)d_out;

    float*          partial = (float*)d_ws;                                   // 16 KB
    unsigned short* ligP    = (unsigned short*)((char*)d_ws + 65536);         // 2 MB
    unsigned short* recP    = (unsigned short*)((char*)d_ws + 65536 + (2u << 20)); // 16 MB

    const int n4_lig = Lc * Ec * Fc / 4;   // 131072
    const int n4_rec = Rc * Ec * Fc / 4;   // 1048576

    ff_cvt<<<(n4_lig + 255) / 256, 256, 0, stream>>>(lig_feat, ligP, n4_lig);
    ff_cvt<<<(n4_rec + 255) / 256, 256, 0, stream>>>(rec_feat, recP, n4_rec);
    ff_mfma<<<NBLKM, 256, 0, stream>>>(ligP, recP, lig_coords, rec_coords, partial);
    ff_reduce<<<1, 512, 0, stream>>>(partial, out);
}

// Round 12
// 54.866 us; speedup vs baseline: 2.4168x; 1.0073x over previous
//
#include <hip/hip_runtime.h>
#include <math.h>

#define Lc 128
#define Rc 1024
#define Pc 8
#define Ec 64
#define Fc 64

// exp(-((d-mu)/sigma)^2) = exp2(-(C*(d-mu))^2), C = (1/0.15625)*sqrt(log2(e))
#define CSCALE   7.68718341623328f
#define MU_STEP  0.15873015873015873f   // 10/63
#define MUC      (MU_STEP * CSCALE)

#define NBLKM 512    // ff_mfma blocks: 16 ng x 8 mt x 4 ez

typedef __attribute__((ext_vector_type(8))) short short8;   // 8 bf16 (4 VGPRs)
typedef __attribute__((ext_vector_type(4))) float f32x4;

__device__ __forceinline__ unsigned short bf16_rn(float x) {
    unsigned int u = __float_as_uint(x);
    u += 0x7FFF + ((u >> 16) & 1);
    return (unsigned short)(u >> 16);
}
__device__ __forceinline__ float bf16_f32(unsigned short b) {
    return __uint_as_float(((unsigned int)b) << 16);
}

// ---- split-convert f32 -> (hi,lo) bf16, layout [g=row*64+e][hi:0..63 | lo:64..127] ----
__global__ __launch_bounds__(256)
void ff_cvt(const float* __restrict__ src, unsigned short* __restrict__ dst, int n4)
{
    int i = blockIdx.x * 256 + threadIdx.x;
    if (i >= n4) return;
    float4 v = ((const float4*)src)[i];
    int s0 = i * 4;
    size_t g = (size_t)(s0 >> 6);
    int kb = s0 & 63;
    ushort4 h, l;
    h.x = bf16_rn(v.x); l.x = bf16_rn(v.x - bf16_f32(h.x));
    h.y = bf16_rn(v.y); l.y = bf16_rn(v.y - bf16_f32(h.y));
    h.z = bf16_rn(v.z); l.z = bf16_rn(v.z - bf16_f32(h.z));
    h.w = bf16_rn(v.w); l.w = bf16_rn(v.w - bf16_f32(h.w));
    *(ushort4*)(dst + g * 128 + kb)      = h;
    *(ushort4*)(dst + g * 128 + 64 + kb) = l;
}

// ---- fused: per (16l x 16r) C-tile, per e: 6 split-MFMAs -> fold exp2 into us[p] ----
// C/D layout (verified): col r = lane&15, row l_off = (lane>>4)*4 + reg.
__global__ __launch_bounds__(256, 2)
void ff_mfma(const unsigned short* __restrict__ ligP,
             const unsigned short* __restrict__ recP,
             const float* __restrict__ lig_coords,
             const float* __restrict__ rec_coords,
             float* __restrict__ partial)
{
    // 64 KB LDS ballast: pins compiler-visible occupancy to 2 blocks/CU
    // (= the real grid occupancy) -> 256-VGPR budget -> no spill.
    // Low words double as the cross-wave reduce scratch (keeps it allocated).
    __shared__ float lds_scratch[16384];

    const int tid  = threadIdx.x;
    const int lane = tid & 63;
    const int w    = tid >> 6;
    const int n16  = lane & 15;
    const int kg   = lane >> 4;

    // bid -> (ng, mt, ez); bid&7 = XCD (round-robin dispatch): each XCD owns
    // 2 n-groups -> 128 rec rows = 2 MB recP slice, L2-resident.
    const int bid = blockIdx.x;
    const int loc = bid >> 3;
    const int ng  = (bid & 7) * 2 + (loc & 1);
    const int mt  = (loc >> 1) & 7;
    const int ez  = loc >> 4;              // 0..3
    const int nt  = ng * 4 + w;            // this wave's ntile 0..63
    const int r   = nt * 16 + n16;
    const int e0  = ez * 16;

    // per-lane distances for (8 poses) x (4 l's of this lane)
    const float rcx = rec_coords[r * 3 + 0];
    const float rcy = rec_coords[r * 3 + 1];
    const float rcz = rec_coords[r * 3 + 2];
    float dsc[Pc][4];
    #pragma unroll
    for (int reg = 0; reg < 4; ++reg) {
        const int l = mt * 16 + kg * 4 + reg;
        #pragma unroll
        for (int p = 0; p < Pc; ++p) {
            const float* lcp = lig_coords + ((size_t)p * Lc + l) * 3;
            float dx = lcp[0] - rcx;
            float dy = lcp[1] - rcy;
            float dz = lcp[2] - rcz;
            dsc[p][reg] = sqrtf(dx * dx + dy * dy + dz * dz) * CSCALE;
        }
    }

    // fragment base pointers (per-lane, 16B loads; e-step advances by 128)
    const unsigned short* ap = ligP + ((size_t)(mt * 16 + n16) * Ec + e0) * 128 + kg * 8;
    const unsigned short* bp = recP + ((size_t)r * Ec + e0) * 128 + kg * 8;

    short8 Ah0 = *(const short8*)(ap);
    short8 Ah1 = *(const short8*)(ap + 32);
    short8 Al0 = *(const short8*)(ap + 64);
    short8 Al1 = *(const short8*)(ap + 96);
    short8 Bh0 = *(const short8*)(bp);
    short8 Bh1 = *(const short8*)(bp + 32);
    short8 Bl0 = *(const short8*)(bp + 64);
    short8 Bl1 = *(const short8*)(bp + 96);

    float us[Pc];
    #pragma unroll
    for (int p = 0; p < Pc; ++p) us[p] = 0.f;

    for (int te = 0; te < 16; ++te) {
        // prefetch next e's fragments (fold below hides the L2 latency)
        short8 nAh0 = Ah0, nAh1 = Ah1, nAl0 = Al0, nAl1 = Al1;
        short8 nBh0 = Bh0, nBh1 = Bh1, nBl0 = Bl0, nBl1 = Bl1;
        if (te < 15) {
            const unsigned short* an = ap + (size_t)(te + 1) * 128;
            const unsigned short* bn = bp + (size_t)(te + 1) * 128;
            nAh0 = *(const short8*)(an);
            nAh1 = *(const short8*)(an + 32);
            nAl0 = *(const short8*)(an + 64);
            nAl1 = *(const short8*)(an + 96);
            nBh0 = *(const short8*)(bn);
            nBh1 = *(const short8*)(bn + 32);
            nBl0 = *(const short8*)(bn + 64);
            nBl1 = *(const short8*)(bn + 96);
        }

        // atn tile for this e: hh + al*bh + ah*bl (drop al*bl, ~2^-18 rel)
        f32x4 acc = {0.f, 0.f, 0.f, 0.f};
        acc = __builtin_amdgcn_mfma_f32_16x16x32_bf16(Ah0, Bh0, acc, 0, 0, 0);
        acc = __builtin_amdgcn_mfma_f32_16x16x32_bf16(Ah1, Bh1, acc, 0, 0, 0);
        acc = __builtin_amdgcn_mfma_f32_16x16x32_bf16(Al0, Bh0, acc, 0, 0, 0);
        acc = __builtin_amdgcn_mfma_f32_16x16x32_bf16(Al1, Bh1, acc, 0, 0, 0);
        acc = __builtin_amdgcn_mfma_f32_16x16x32_bf16(Ah0, Bl0, acc, 0, 0, 0);
        acc = __builtin_amdgcn_mfma_f32_16x16x32_bf16(Ah1, Bl1, acc, 0, 0, 0);

        // fold into pose accumulators
        const float musC = (float)(e0 + te) * MUC;
        #pragma unroll
        for (int reg = 0; reg < 4; ++reg) {
            const float a = acc[reg];
            #pragma unroll
            for (int p = 0; p < Pc; ++p) {
                const float t = dsc[p][reg] - musC;
                us[p] = fmaf(a, __builtin_amdgcn_exp2f(-(t * t)), us[p]);
            }
        }

        Ah0 = nAh0; Ah1 = nAh1; Al0 = nAl0; Al1 = nAl1;
        Bh0 = nBh0; Bh1 = nBh1; Bl0 = nBl0; Bl1 = nBl1;
    }

    // butterfly over 64 lanes, then across the 4 waves
    #pragma unroll
    for (int p = 0; p < Pc; ++p) {
        float v = us[p];
        #pragma unroll
        for (int off = 32; off >= 1; off >>= 1)
            v += __shfl_xor(v, off, 64);
        us[p] = v;
    }
    if (lane == 0) {
        #pragma unroll
        for (int p = 0; p < Pc; ++p) lds_scratch[w * Pc + p] = us[p];
    }
    __syncthreads();
    if (tid < Pc) {
        float s = 0.f;
        #pragma unroll
        for (int k = 0; k < 4; ++k) s += lds_scratch[k * Pc + tid];
        partial[(size_t)bid * Pc + tid] = s;
    }
}

// reduce NBLKM block-partials x 8 poses -> 8 outputs
__global__ void ff_reduce(const float* __restrict__ partial, float* __restrict__ out)
{
    const int w    = threadIdx.x >> 6;
    const int lane = threadIdx.x & 63;
    float v = 0.f;
    #pragma unroll
    for (int j = 0; j < NBLKM / 64; ++j)
        v += partial[(size_t)(lane + 64 * j) * Pc + w];
    #pragma unroll
    for (int off = 32; off >= 1; off >>= 1)
        v += __shfl_xor(v, off, 64);
    if (lane == 0) out[w] = 0.1f * v;
}

extern "C" void kernel_launch(void* const* d_in, const int* in_sizes, int n_in,
                              void* d_out, int out_size, void* d_ws, size_t ws_size,
                              hipStream_t stream)
{
    const float* lig_feat   = (const float*)d_in[0];
    const float* rec_feat   = (const float*)d_in[1];
    const float* lig_coords = (const float*)d_in[2];
    const float* rec_coords = (const float*)d_in[3];
    float* out = (float*)d_out;

    float*          partial = (float*)d_ws;                                   // 16 KB
    unsigned short* ligP    = (unsigned short*)((char*)d_ws + 65536);         // 2 MB
    unsigned short* recP    = (unsigned short*)((char*)d_ws + 65536 + (2u << 20)); // 16 MB

    const int n4_lig = Lc * Ec * Fc / 4;   // 131072
    const int n4_rec = Rc * Ec * Fc / 4;   // 1048576

    ff_cvt<<<(n4_lig + 255) / 256, 256, 0, stream>>>(lig_feat, ligP, n4_lig);
    ff_cvt<<<(n4_rec + 255) / 256, 256, 0, stream>>>(rec_feat, recP, n4_rec);
    ff_mfma<<<NBLKM, 256, 0, stream>>>(ligP, recP, lig_coords, rec_coords, partial);
    ff_reduce<<<1, 512, 0, stream>>>(partial, out);
}